// Round 1
// 899.343 us; speedup vs baseline: 1.0420x; 1.0420x over previous
//
#include <hip/hip_runtime.h>
#include <hip/hip_bf16.h>

typedef unsigned int u32;
typedef _Float16     f16;
typedef f16   f16x8v __attribute__((ext_vector_type(8)));
typedef float f32x4  __attribute__((ext_vector_type(4)));

#define GX_BYTES ((size_t)65536 * 1024 * 2)

__device__ __forceinline__ float sigm(float x) {
    return __builtin_amdgcn_rcpf(1.0f + __expf(-x));
}
__device__ __forceinline__ float tanh_f(float x) {
    return 1.0f - 2.0f * __builtin_amdgcn_rcpf(__expf(2.0f * x) + 1.0f);
}
__device__ __forceinline__ f16x8v pack8(float4 a, float4 b) {
    f16x8v v;
    v[0] = (f16)a.x; v[1] = (f16)a.y; v[2] = (f16)a.z; v[3] = (f16)a.w;
    v[4] = (f16)b.x; v[5] = (f16)b.y; v[6] = (f16)b.z; v[7] = (f16)b.w;
    return v;
}

// ---------------------------------------------------------------------------
// Kernel 1: gates_x = x @ Wg[:, :256]^T + bg  -> f16 [65536][1024]
// (unchanged GEMM — plus: zero the 256 KB h-exchange mailbox so stale tags
//  from a previous graph replay can never satisfy this run's polls)
// ---------------------------------------------------------------------------
__global__ __launch_bounds__(256) void gemm_gx(
    const float* __restrict__ X,
    const float* __restrict__ Wf, const float* __restrict__ Wi,
    const float* __restrict__ Wc, const float* __restrict__ Wo,
    const float* __restrict__ bf_, const float* __restrict__ bi_,
    const float* __restrict__ bc_, const float* __restrict__ bo_,
    f16* __restrict__ gx, u32* __restrict__ hx) {
    __shared__ _Float16 As[128 * 40];
    __shared__ _Float16 Bs[128 * 40];
    __shared__ float bias_lds[128];

    const int tid = threadIdx.x;
    const int wgy = blockIdx.y;
    const size_t m0 = (size_t)blockIdx.x * 128;

    // zero mailbox: 65536 u32 = 16384 int4, done by wgy==0 blocks
    if (wgy == 0) {
        const int gid = blockIdx.x * 256 + tid;
        if (gid < 16384) {
            int4 z; z.x = 0; z.y = 0; z.z = 0; z.w = 0;
            ((int4*)hx)[gid] = z;
        }
    }

    const float* Wsel[4] = {Wf, Wi, Wc, Wo};
    const float* bsel[4] = {bf_, bi_, bc_, bo_};
    const float* Wseg = Wsel[wgy >> 1];
    const int row_off = (wgy & 1) * 128;

    if (tid < 128) bias_lds[tid] = bsel[wgy >> 1][row_off + tid];

    const int r  = tid >> 2;
    const int c8 = (tid & 3) * 8;

    const float* Ap0 = X + (m0 + r) * 256 + c8;
    const float* Ap1 = Ap0 + 64 * 256;
    const float* Bp0 = Wseg + (size_t)(row_off + r) * 512 + c8;
    const float* Bp1 = Bp0 + 64 * 512;

    const int lane = tid & 63;
    const int w    = tid >> 6;
    const int wm = w >> 1, wn = w & 1;
    const int col = lane & 15, quad = lane >> 4;

    f32x4 acc[4][4] = {};

    for (int kc = 0; kc < 8; kc++) {
        const int kk = kc * 32;
        float4 a00 = *(const float4*)(Ap0 + kk);
        float4 a01 = *(const float4*)(Ap0 + kk + 4);
        float4 a10 = *(const float4*)(Ap1 + kk);
        float4 a11 = *(const float4*)(Ap1 + kk + 4);
        float4 b00 = *(const float4*)(Bp0 + kk);
        float4 b01 = *(const float4*)(Bp0 + kk + 4);
        float4 b10 = *(const float4*)(Bp1 + kk);
        float4 b11 = *(const float4*)(Bp1 + kk + 4);
        __syncthreads();
        *(f16x8v*)&As[r * 40 + c8]        = pack8(a00, a01);
        *(f16x8v*)&As[(r + 64) * 40 + c8] = pack8(a10, a11);
        *(f16x8v*)&Bs[r * 40 + c8]        = pack8(b00, b01);
        *(f16x8v*)&Bs[(r + 64) * 40 + c8] = pack8(b10, b11);
        __syncthreads();
        f16x8v a[4], b[4];
        #pragma unroll
        for (int i = 0; i < 4; i++)
            a[i] = *(const f16x8v*)&As[(wm * 64 + i * 16 + col) * 40 + quad * 8];
        #pragma unroll
        for (int j = 0; j < 4; j++)
            b[j] = *(const f16x8v*)&Bs[(wn * 64 + j * 16 + col) * 40 + quad * 8];
        #pragma unroll
        for (int i = 0; i < 4; i++)
            #pragma unroll
            for (int j = 0; j < 4; j++)
                acc[i][j] = __builtin_amdgcn_mfma_f32_16x16x32_f16(a[i], b[j], acc[i][j], 0, 0, 0);
    }

    #pragma unroll
    for (int i = 0; i < 4; i++) {
        #pragma unroll
        for (int j = 0; j < 4; j++) {
            #pragma unroll
            for (int rg = 0; rg < 4; rg++) {
                const size_t m = m0 + wm * 64 + i * 16 + quad * 4 + rg;
                const int nl = wn * 64 + j * 16 + col;
                gx[m * 1024 + (size_t)wgy * 128 + nl] = (f16)(acc[i][j][rg] + bias_lds[nl]);
            }
        }
    }
}

// ---------------------------------------------------------------------------
// Kernel 2: the recurrence, gate-split across TWO WGs per batch.
// 256 WGs x 512 thr -> all 256 CUs. WG (b,s) owns units [128s, 128s+128):
// wave w owns 16 units (u = 128s + 16w + l15), all 4 gates = 4 col-tiles,
// 32 MFMA/wave/step (64/SIMD ~ 1033 cyc vs 2067 before). All 4x8 weight
// fragments are register-resident (128 regs) -> no LDS weight streaming.
//
// Cross-WG h exchange: each unit's new h is published as ONE u32 word
//   (f16 bits << 16) | (t+1)
// with relaxed AGENT-scope atomics into a double-buffered mailbox slot
// (t+1)&1. Words are self-validating (tag == t+1), so no fences/flags.
// Slot-reuse safety: partner can only overwrite slot with h_{t+3} after it
// consumed our h_{t+1} (its step t+1 needs our h_{t+1}-half) — race-free.
// Wave 0 polls the partner's 128 words and stages them into the LDS h
// double-buffer; ONE barrier per step. Pair (b, b+128) -> same XCD under
// round-robin dispatch (perf), but agent scope keeps it correct anywhere.
// Mailbox zeroed by gemm_gx each replay (stale tags from a prior replay
// would otherwise match this run's polls after input re-poisoning).
// ---------------------------------------------------------------------------
__global__ __launch_bounds__(512, 2) void lstm_rec(
    const float* __restrict__ Wf, const float* __restrict__ Wi,
    const float* __restrict__ Wc, const float* __restrict__ Wo,
    const f16* __restrict__ gx,
    const float* __restrict__ Wout, const float* __restrict__ bout,
    u32* hx,
    float* __restrict__ out) {
    __shared__ _Float16 hbuf[2][256] __attribute__((aligned(16)));

    const int tid  = threadIdx.x;
    const int bb   = blockIdx.x;
    const int b    = bb & 127;          // batch
    const int s    = bb >> 7;           // unit-half: 0 or 1
    const int w    = tid >> 6;          // wave 0..7
    const int l    = tid & 63;
    const int l15  = l & 15;
    const int quad = l >> 4;

    const int u_loc = 16 * w + l15;     // 0..127 within this WG's half
    const int u     = 128 * s + u_loc;  // absolute unit 0..255

    // --- register-resident B fragments: wB[g][kt], g in {f,i,c,o} ---
    f16x8v wB[4][8];
    {
        const float* gp[4] = {Wf, Wi, Wc, Wo};
        #pragma unroll
        for (int g = 0; g < 4; g++) {
            const float* row = gp[g] + (size_t)u * 512 + 256 + quad * 8;
            #pragma unroll
            for (int kt = 0; kt < 8; kt++) {
                float4 x0 = *(const float4*)(row + kt * 32);
                float4 x1 = *(const float4*)(row + kt * 32 + 4);
                wB[g][kt] = pack8(x0, x1);
            }
        }
    }

    float c = 0.0f;
    if (tid < 256) hbuf[0][tid] = (f16)0.0f;   // h_0 = 0 (both halves)

    u32*       hx_pub = hx + (size_t)(b * 2 + s)       * 256;  // 2 slots x 128
    u32*       hx_par = hx + (size_t)(b * 2 + (1 - s)) * 256;

    const f16* gxr = gx + (size_t)b * 512 * 1024 + u;
    float pf  = (float)gxr[0];
    float pi_ = (float)gxr[256];
    float pg  = (float)gxr[512];
    float po  = (float)gxr[768];

    const f32x4 Zc = {0.f, 0.f, 0.f, 0.f};

    __syncthreads();   // h_0 visible

    for (int t = 0; t < 512; t++) {
        float gf = pf, gi = pi_, gg = pg, go = po;
        {   // branchless prefetch of next step's x-gates
            const f16* gn = gxr + (size_t)(t < 511 ? t + 1 : 511) * 1024;
            pf  = (float)gn[0];
            pi_ = (float)gn[256];
            pg  = (float)gn[512];
            po  = (float)gn[768];
        }

        // --- gates: D = h_t @ W_h^T for this wave's 16 units x 4 gates ---
        const _Float16* hA = &hbuf[t & 1][quad * 8];
        f32x4 acc[4];
        #pragma unroll
        for (int kt = 0; kt < 8; kt++) {
            f16x8v A = *(const f16x8v*)&hA[kt * 32];
            if (kt == 0) {
                #pragma unroll
                for (int g = 0; g < 4; g++)
                    acc[g] = __builtin_amdgcn_mfma_f32_16x16x32_f16(A, wB[g][0], Zc, 0, 0, 0);
            } else {
                #pragma unroll
                for (int g = 0; g < 4; g++)
                    acc[g] = __builtin_amdgcn_mfma_f32_16x16x32_f16(A, wB[g][kt], acc[g], 0, 0, 0);
            }
        }

        // rows of D replicated -> reg 0 of each tile is this lane's unit value
        float F = gf + acc[0][0];
        float I = gi + acc[1][0];
        float G = gg + acc[2][0];
        float O = go + acc[3][0];
        float sf = sigm(F), si = sigm(I), so = sigm(O);
        float tg = tanh_f(G);
        c = c * sf + si * tg;
        float h = tanh_f(c) * so;

        const int ns = (t + 1) & 1;
        const f16 h16v = (f16)h;

        // publish own half (one writer lane per unit) + own LDS write
        if (quad == 0) {
            hbuf[ns][u] = h16v;
            u32 word = ((u32)__builtin_bit_cast(unsigned short, h16v) << 16)
                     | (u32)(t + 1);
            __hip_atomic_store(hx_pub + ns * 128 + u_loc, word,
                               __ATOMIC_RELAXED, __HIP_MEMORY_SCOPE_AGENT);
        }

        // wave 0: pull partner half into LDS (tagged-word poll)
        if (w == 0) {
            const u32 want = (u32)(t + 1);
            u32* pp = hx_par + ns * 128;
            u32 w0, w1;
            int spin = 0;
            for (;;) {
                w0 = __hip_atomic_load(pp + l,      __ATOMIC_RELAXED, __HIP_MEMORY_SCOPE_AGENT);
                w1 = __hip_atomic_load(pp + l + 64, __ATOMIC_RELAXED, __HIP_MEMORY_SCOPE_AGENT);
                int ok = ((w0 & 0xFFFFu) == want) & ((w1 & 0xFFFFu) == want);
                if (__all(ok) || ++spin > (1 << 20)) break;   // bound: never hang
            }
            const int po_ = 128 * (1 - s);
            hbuf[ns][po_ + l]      = __builtin_bit_cast(_Float16, (unsigned short)(w0 >> 16));
            hbuf[ns][po_ + l + 64] = __builtin_bit_cast(_Float16, (unsigned short)(w1 >> 16));
        }

        __syncthreads();   // h_{t+1} (both halves) visible; also guards hbuf reuse
    }

    // out[b, 64s : 64s+64] = h_final @ Wout^T + bout   (h_512 is in hbuf[0])
    if (tid < 64) {
        const int r = 64 * s + tid;
        float acc = bout[r];
        const float4* wv = (const float4*)(Wout + (size_t)r * 256);
        #pragma unroll
        for (int q = 0; q < 64; q++) {
            float4 v = wv[q];
            acc += v.x * (float)hbuf[0][q * 4 + 0];
            acc += v.y * (float)hbuf[0][q * 4 + 1];
            acc += v.z * (float)hbuf[0][q * 4 + 2];
            acc += v.w * (float)hbuf[0][q * 4 + 3];
        }
        out[b * 128 + r] = acc;
    }
}

extern "C" void kernel_launch(void* const* d_in, const int* in_sizes, int n_in,
                              void* d_out, int out_size, void* d_ws, size_t ws_size,
                              hipStream_t stream) {
    const float* x    = (const float*)d_in[0];
    const float* Wf   = (const float*)d_in[1];
    const float* bfv  = (const float*)d_in[2];
    const float* Wi   = (const float*)d_in[3];
    const float* biv  = (const float*)d_in[4];
    const float* Wc   = (const float*)d_in[5];
    const float* bcv  = (const float*)d_in[6];
    const float* Wo   = (const float*)d_in[7];
    const float* bov  = (const float*)d_in[8];
    const float* Wout = (const float*)d_in[9];
    const float* bout = (const float*)d_in[10];

    f16* gx = (f16*)d_ws;
    u32* hx = (u32*)((char*)d_ws + GX_BYTES);   // 256 KB mailbox after gx

    gemm_gx<<<dim3(512, 8), 256, 0, stream>>>(x, Wf, Wi, Wc, Wo, bfv, biv, bcv, bov, gx, hx);
    lstm_rec<<<256, 512, 0, stream>>>(Wf, Wi, Wc, Wo, gx, Wout, bout, hx, (float*)d_out);
}